// Round 4
// baseline (601.496 us; speedup 1.0000x reference)
//
#include <hip/hip_runtime.h>
#include <hip/hip_fp16.h>

// GCN: h1 = relu(gcn(x,W1,b1)); h2 = relu(gcn(h1,W2,b2)); out = h2.reshape(B,896)@Wfc + bfc
// Factored BOTH layers past the aggregation (agg commutes with @W):
//   P  = dinv*x (fp16, 32 feat = 64B rows)           <- stage-1 gather table
//   u1 = dinv*relu(dinv*(agg(P)@W1)+b1)  (fp16, 64 feat)
//   out= FC(relu((dinv*agg(u1))@W2+b2))
// CSR via deterministic counting sort (b=dst>>11), self-loop in-row, dummy zero row at N.
// POSITION-SPACE DEGREE SORT: nodes are counting-sorted by degree into perm[]/iperm[];
// the gather tables P,U are STORED in permuted order, col[] values are remapped to
// positions, and rowinfo/dinv_p are pre-permuted. So 16-position MFMA tiles have
// near-uniform degree (minimal gather-loop padding) AND keep coalesced table writes
// and contiguous self-gathers (self entry of position p is p -> the tile's own rows).
// Gather loops use the MFMA fragment layout: lane(m=lane&15, quad=lane>>4) owns 16B chunks
// of row m; clamped col -> unconditional dwordx4 gathers, pk_add fp16.

typedef _Float16 half8 __attribute__((ext_vector_type(8)));
typedef float float4v __attribute__((ext_vector_type(4)));

#define CHUNK 8192
#define BSH 11
#define BNODES 2048
#define DBINS 64

__global__ __launch_bounds__(256) void fallback_kernel(float* __restrict__ out, int n, float v)
{
  int i = blockIdx.x * 256 + threadIdx.x;
  if (i < n) out[i] = v;
}

// detect edges dtype: int64 values < 2^31 -> every odd int32 word is 0
__global__ __launch_bounds__(64) void probe_kernel(const int* __restrict__ edges, int* __restrict__ flag)
{
  if (threadIdx.x == 0) {
    int orv = edges[1] | edges[3] | edges[5] | edges[7] | edges[9] | edges[11] | edges[13] | edges[15];
    flag[0] = (orv == 0) ? 1 : 0;  // 1 => int64 layout (shift word index by 1)
  }
}

// zero the dummy rows (index N): P row = 64B, F2 row = 128B; also zero degree hist.
__global__ __launch_bounds__(64) void zero_dummy_kernel(
    __half* __restrict__ P, __half* __restrict__ F2, int* __restrict__ dhist, int N)
{
  int t = threadIdx.x;
  dhist[t] = 0;
  if (t < 8) ((uint2*)(P + (size_t)N * 32))[t] = make_uint2(0, 0);
  else if (t < 24) ((uint2*)(F2 + (size_t)N * 64))[t - 8] = make_uint2(0, 0);
}

// (1) per-chunk bucket histogram -> cnt[chunk][b]
__global__ __launch_bounds__(256) void hist2_kernel(
    const int* __restrict__ edges, int E, int N, const int* __restrict__ flag,
    int* __restrict__ cnt, int NBK)
{
  __shared__ int lh[512];
  int t = threadIdx.x;
  int blk = blockIdx.x;
  for (int b = t; b < NBK; b += 256) lh[b] = 0;
  __syncthreads();
  int sh = flag[0];
  int base = blk * CHUNK;
#pragma unroll
  for (int k = 0; k < CHUNK / 256; k++) {
    int e = base + k * 256 + t;
    if (e < E) {
      int d = edges[(E + e) << sh];
      if ((unsigned)d < (unsigned)N) atomicAdd(&lh[d >> BSH], 1);
    }
  }
  __syncthreads();
  for (int b = t; b < NBK; b += 256) cnt[(size_t)blk * NBK + b] = lh[b];
}

// (2) per-bucket exclusive prefix over chunks, in place; totals[b] = column sum
__global__ __launch_bounds__(64) void colscan_kernel(
    int* __restrict__ cnt, int NCH, int NBK, int* __restrict__ totals)
{
  int b = blockIdx.x;
  int lane = threadIdx.x;
  int carry = 0;
  int rounds = (NCH + 63) >> 6;
  for (int r = 0; r < rounds; r++) {
    int blk = r * 64 + lane;
    int v = (blk < NCH) ? cnt[(size_t)blk * NBK + b] : 0;
    int incl = v;
#pragma unroll
    for (int off = 1; off < 64; off <<= 1) {
      int x = __shfl_up(incl, off);
      if (lane >= off) incl += x;
    }
    int excl = incl - v + carry;
    if (blk < NCH) cnt[(size_t)blk * NBK + b] = excl;
    carry += __shfl(incl, 63);
  }
  if (lane == 0) totals[b] = carry;
}

// (3) exclusive scan of bucket totals -> bstart[NBK+1]; rowptr[N] = Ev + N
__global__ __launch_bounds__(512) void scan_totals_kernel(
    const int* __restrict__ totals, int NBK,
    int* __restrict__ bstart, int* __restrict__ rowptr, int N)
{
  __shared__ int sm[512];
  int t = threadIdx.x;
  int v = (t < NBK) ? totals[t] : 0;
  sm[t] = v;
  __syncthreads();
  for (int off = 1; off < 512; off <<= 1) {
    int x = 0;
    if (t >= off) x = sm[t - off];
    __syncthreads();
    if (t >= off) sm[t] += x;
    __syncthreads();
  }
  if (t < NBK) bstart[t] = sm[t] - v;
  if (t == 0) { bstart[NBK] = sm[511]; rowptr[N] = sm[511] + N; }
}

// (4) placement: contiguous runs per (chunk,bucket); packed = src | (dst&2047)<<20
__global__ __launch_bounds__(256) void pass3_kernel(
    const int* __restrict__ edges, int E, int N, const int* __restrict__ flag,
    const int* __restrict__ cnt, const int* __restrict__ bstart,
    int* __restrict__ pair, int NBK)
{
  __shared__ int lcur[512];
  int t = threadIdx.x;
  int blk = blockIdx.x;
  for (int b = t; b < NBK; b += 256)
    lcur[b] = bstart[b] + cnt[(size_t)blk * NBK + b];
  __syncthreads();
  int sh = flag[0];
  int base = blk * CHUNK;
#pragma unroll
  for (int k = 0; k < CHUNK / 256; k++) {
    int e = base + k * 256 + t;
    if (e < E) {
      int s = edges[e << sh];
      int d = edges[(E + e) << sh];
      if ((unsigned)s < (unsigned)N && (unsigned)d < (unsigned)N) {
        int pos = atomicAdd(&lcur[d >> BSH], 1);
        pair[pos] = s | ((d & (BNODES - 1)) << 20);
      }
    }
  }
}

// (5) per-bucket CSR build with self entry first in each row.
__global__ __launch_bounds__(256) void build_kernel(
    const int* __restrict__ pair, const int* __restrict__ bstart,
    int* __restrict__ rowptr, float* __restrict__ dinv, int* __restrict__ col, int N)
{
  __shared__ int hist[BNODES];
  __shared__ int cur[BNODES];
  __shared__ int sc[256];
  int b = blockIdx.x;
  int t = threadIdx.x;
  int pbeg = bstart[b], pend = bstart[b + 1];
  int colbase = pbeg + (b << BSH);
#pragma unroll
  for (int i = 0; i < BNODES / 256; i++) {
    int idx = i * 256 + t;
    int row = (b << BSH) + idx;
    hist[idx] = (row < N) ? 1 : 0;  // self entry
  }
  __syncthreads();
  for (int p = pbeg + t; p < pend; p += 256)
    atomicAdd(&hist[(pair[p] >> 20) & (BNODES - 1)], 1);
  __syncthreads();
  int hv[8];
  int tsum = 0;
#pragma unroll
  for (int i = 0; i < 8; i++) { hv[i] = hist[t * 8 + i]; tsum += hv[i]; }
  sc[t] = tsum;
  __syncthreads();
  for (int off = 1; off < 256; off <<= 1) {
    int x = 0;
    if (t >= off) x = sc[t - off];
    __syncthreads();
    if (t >= off) sc[t] += x;
    __syncthreads();
  }
  int run = sc[t] - tsum;
#pragma unroll
  for (int i = 0; i < 8; i++) {
    int idx = t * 8 + i;
    int rp = colbase + run;
    int row = (b << BSH) + idx;
    if (row < N) {
      rowptr[row] = rp;
      dinv[row] = rsqrtf((float)hv[i]);  // hv = deg + 1 (self included)
      col[rp] = row;                      // self entry at slot 0
      cur[idx] = rp + 1;
    } else {
      cur[idx] = rp;
    }
    run += hv[i];
  }
  __syncthreads();
  for (int p = pbeg + t; p < pend; p += 256) {
    int v = pair[p];
    int pos = atomicAdd(&cur[(v >> 20) & (BNODES - 1)], 1);
    col[pos] = v & 0xFFFFF;
  }
}

// (6) degree histogram over nodes (bin = min(rlen, 63))
__global__ __launch_bounds__(256) void deg_hist_kernel(
    const int* __restrict__ rowptr, int* __restrict__ dhist, int N)
{
  __shared__ int lh[DBINS];
  int t = threadIdx.x;
  if (t < DBINS) lh[t] = 0;
  __syncthreads();
  int n = blockIdx.x * 256 + t;
  if (n < N) {
    int rlen = rowptr[n + 1] - rowptr[n];
    int b = rlen < DBINS ? rlen : DBINS - 1;
    atomicAdd(&lh[b], 1);
  }
  __syncthreads();
  if (t < DBINS && lh[t]) atomicAdd(&dhist[t], lh[t]);
}

// (7) exclusive scan of 64 bins -> dcur (running cursors for placement)
__global__ __launch_bounds__(64) void deg_scan_kernel(
    const int* __restrict__ dhist, int* __restrict__ dcur)
{
  int t = threadIdx.x;
  int v = dhist[t];
  int incl = v;
#pragma unroll
  for (int off = 1; off < 64; off <<= 1) {
    int x = __shfl_up(incl, off);
    if (t >= off) incl += x;
  }
  dcur[t] = incl - v;
}

// (8) place nodes into position space grouped by degree bin; emit perm, iperm,
// pre-permuted rowinfo {rbeg,rlen} and dinv_p.
__global__ __launch_bounds__(256) void deg_place_kernel(
    const int* __restrict__ rowptr, const float* __restrict__ dinv, int* __restrict__ dcur,
    int* __restrict__ perm, int* __restrict__ iperm,
    int2* __restrict__ rowinfo, float* __restrict__ dinv_p, int N)
{
  __shared__ int lh[DBINS];
  __shared__ int lbase[DBINS];
  int t = threadIdx.x;
  if (t < DBINS) lh[t] = 0;
  __syncthreads();
  int n = blockIdx.x * 256 + t;
  int b = -1, rbeg = 0, rlen = 0;
  if (n < N) {
    rbeg = rowptr[n];
    rlen = rowptr[n + 1] - rbeg;
    b = rlen < DBINS ? rlen : DBINS - 1;
    atomicAdd(&lh[b], 1);
  }
  __syncthreads();
  if (t < DBINS) lbase[t] = lh[t] ? atomicAdd(&dcur[t], lh[t]) : 0;
  __syncthreads();
  if (t < DBINS) lh[t] = lbase[t];  // reuse lh as intra-block cursor
  __syncthreads();
  if (n < N) {
    int pos = atomicAdd(&lh[b], 1);
    perm[pos] = n;
    iperm[n] = pos;
    rowinfo[pos] = make_int2(rbeg, rlen);
    dinv_p[pos] = dinv[n];
  }
}

// (9) remap col[] values node-id -> position (iperm is L2-resident, 2.8MB)
__global__ __launch_bounds__(256) void remap_col_kernel(
    int* __restrict__ col, const int* __restrict__ iperm,
    const int* __restrict__ rowptr, int N)
{
  int total = rowptr[N];  // Ev + N (uniform per wave -> scalar load)
  int stride = gridDim.x * 256;
  for (int k = blockIdx.x * 256 + threadIdx.x; k < total; k += stride)
    col[k] = iperm[col[k]];
}

// P[pos] = dinv_p[pos] * x[perm[pos]], fp16, 32 feat = 64B rows. 4 threads/row.
__global__ __launch_bounds__(256) void scale_x_perm_kernel(
    const float* __restrict__ X, const int* __restrict__ perm,
    const float* __restrict__ dinv_p, __half* __restrict__ P, int N)
{
  int idx = blockIdx.x * 256 + threadIdx.x;
  int total = N * 4;
  int stride = gridDim.x * 256;
  for (int i = idx; i < total; i += stride) {
    int pos = i >> 2, part = i & 3;
    int node = perm[pos];
    const float4* xp = (const float4*)(X + (size_t)node * 32 + part * 8);
    float dv = dinv_p[pos];
    float4 v0 = xp[0], v1 = xp[1];
    half8 h;
    h[0] = (_Float16)(dv * v0.x); h[1] = (_Float16)(dv * v0.y);
    h[2] = (_Float16)(dv * v0.z); h[3] = (_Float16)(dv * v0.w);
    h[4] = (_Float16)(dv * v1.x); h[5] = (_Float16)(dv * v1.y);
    h[6] = (_Float16)(dv * v1.z); h[7] = (_Float16)(dv * v1.w);
    *(half8*)(P + (size_t)pos * 32 + part * 8) = h;
  }
}

__device__ inline void hacc(uint4 v, __half2* a)
{
  a[0] = __hadd2(a[0], *reinterpret_cast<__half2*>(&v.x));
  a[1] = __hadd2(a[1], *reinterpret_cast<__half2*>(&v.y));
  a[2] = __hadd2(a[2], *reinterpret_cast<__half2*>(&v.z));
  a[3] = __hadd2(a[3], *reinterpret_cast<__half2*>(&v.w));
}

// FUSED agg1 + W1 matmul + bias + relu + dinv scale, fully in position space.
// rowinfo/dinv_p coalesced; col values are positions; U written coalesced at
// pos2 = base+quad*4+r; self-gathers hit the tile's own contiguous rows.
__global__ __launch_bounds__(256) void agg1_pos_kernel(
    const __half* __restrict__ P, const int2* __restrict__ rowinfo,
    const int* __restrict__ col, const float* __restrict__ dinv_p,
    const float* __restrict__ W1, const float* __restrict__ b1,
    __half* __restrict__ U, int ntiles, int ndummy)
{
  int lane = threadIdx.x & 63;
  int n16 = lane & 15;
  int quad = lane >> 4;

  half8 bf[4];
#pragma unroll
  for (int jb = 0; jb < 4; jb++)
#pragma unroll
    for (int i = 0; i < 8; i++)
      bf[jb][i] = (_Float16)W1[(quad * 8 + i) * 64 + jb * 16 + n16];
  float b1j[4];
#pragma unroll
  for (int jb = 0; jb < 4; jb++) b1j[jb] = b1[jb * 16 + n16];

  const uint4* P4 = (const uint4*)P;
  _Float16* Uh = (_Float16*)U;
  int wave = (blockIdx.x * 256 + threadIdx.x) >> 6;
  int nw = (gridDim.x * 256) >> 6;
  for (int tile = wave; tile < ntiles; tile += nw) {
    int ut = __builtin_amdgcn_readfirstlane(tile);
    int base = ut * 16;
    int2 ri = rowinfo[base + n16];
    int rbeg = ri.x, rlen = ri.y;
    float dvown = dinv_p[base + n16];

    __half2 z2 = __float2half2_rn(0.f);
    __half2 aA[4] = {z2, z2, z2, z2};
    __half2 aB[4] = {z2, z2, z2, z2};

    for (int j = 0; __any(j < rlen); j += 8) {
      int c[8];
#pragma unroll
      for (int q = 0; q < 8; q++) {
        int cc = col[rbeg + j + q];  // slack-padded overread ok
        c[q] = (j + q < rlen) ? cc : ndummy;
      }
      uint4 v[8];
#pragma unroll
      for (int q = 0; q < 8; q++) v[q] = P4[((size_t)c[q] << 2) + quad];
#pragma unroll
      for (int q = 0; q < 8; q += 2) { hacc(v[q], aA); hacc(v[q + 1], aB); }
    }
#pragma unroll
    for (int k = 0; k < 4; k++) aA[k] = __hadd2(aA[k], aB[k]);

    half8 a = *reinterpret_cast<half8*>(aA);
    float4v co[4];
#pragma unroll
    for (int jb = 0; jb < 4; jb++) {
      float4v z = {0.f, 0.f, 0.f, 0.f};
      co[jb] = __builtin_amdgcn_mfma_f32_16x16x32_f16(a, bf[jb], z, 0, 0, 0);
    }
#pragma unroll
    for (int r = 0; r < 4; r++) {
      int pos2 = base + quad * 4 + r;            // contiguous -> coalesced store
      float dv = __shfl(dvown, quad * 4 + r);    // dinv_p[pos2]
#pragma unroll
      for (int jb = 0; jb < 4; jb++) {
        float h = dv * co[jb][r] + b1j[jb];
        h = h > 0.f ? h : 0.f;
        Uh[(size_t)pos2 * 64 + jb * 16 + n16] = (_Float16)(dv * h);
      }
    }
  }
}

__global__ __launch_bounds__(256) void out_init_kernel(
    float* __restrict__ out, const float* __restrict__ bfc, int n)
{
  int i = blockIdx.x * 256 + threadIdx.x;
  if (i < n) out[i] = bfc[0];
}

// FUSED agg2 + layer2-matmul + relu + FC, position space. perm only for graph ids.
__global__ __launch_bounds__(256) void mfma_final_fused_kernel(
    const __half* __restrict__ U, const int2* __restrict__ rowinfo,
    const int* __restrict__ col, const float* __restrict__ dinv_p,
    const int* __restrict__ perm,
    const float* __restrict__ W2, const float* __restrict__ b2,
    const float* __restrict__ Wfc, float* __restrict__ out,
    int ntiles, int ndummy)
{
  int lane = threadIdx.x & 63;
  int n16 = lane & 15;
  int quad = lane >> 4;

  half8 bf[4][2];
#pragma unroll
  for (int jb = 0; jb < 4; jb++)
#pragma unroll
    for (int kf = 0; kf < 2; kf++)
#pragma unroll
      for (int i = 0; i < 8; i++)
        bf[jb][kf][i] = (_Float16)W2[(kf * 32 + quad * 8 + i) * 64 + jb * 16 + n16];
  float b2j[4];
#pragma unroll
  for (int jb = 0; jb < 4; jb++) b2j[jb] = b2[jb * 16 + n16];

  const uint4* U4 = (const uint4*)U;
  int wave = (blockIdx.x * 256 + threadIdx.x) >> 6;
  int nw = (gridDim.x * 256) >> 6;
  for (int tile = wave; tile < ntiles; tile += nw) {
    int ut = __builtin_amdgcn_readfirstlane(tile);
    int base = ut * 16;
    int2 ri = rowinfo[base + n16];
    int rbeg = ri.x, rlen = ri.y;
    int node = perm[base + n16];  // original id (graph/slot decode only)
    float dvown = dinv_p[base + n16];

    __half2 z2 = __float2half2_rn(0.f);
    __half2 aE0[4] = {z2, z2, z2, z2};
    __half2 aE1[4] = {z2, z2, z2, z2};
    __half2 aO0[4] = {z2, z2, z2, z2};
    __half2 aO1[4] = {z2, z2, z2, z2};

    for (int j = 0; __any(j < rlen); j += 4) {
      int c0 = col[rbeg + j];
      int c1 = col[rbeg + j + 1];  // slack-padded overread ok
      int c2 = col[rbeg + j + 2];
      int c3 = col[rbeg + j + 3];
      c0 = (j < rlen) ? c0 : ndummy;
      c1 = (j + 1 < rlen) ? c1 : ndummy;
      c2 = (j + 2 < rlen) ? c2 : ndummy;
      c3 = (j + 3 < rlen) ? c3 : ndummy;
      uint4 v00 = U4[((size_t)c0 << 3) + quad];
      uint4 v01 = U4[((size_t)c0 << 3) + 4 + quad];
      uint4 v10 = U4[((size_t)c1 << 3) + quad];
      uint4 v11 = U4[((size_t)c1 << 3) + 4 + quad];
      uint4 v20 = U4[((size_t)c2 << 3) + quad];
      uint4 v21 = U4[((size_t)c2 << 3) + 4 + quad];
      uint4 v30 = U4[((size_t)c3 << 3) + quad];
      uint4 v31 = U4[((size_t)c3 << 3) + 4 + quad];
      hacc(v00, aE0); hacc(v01, aE1);
      hacc(v10, aO0); hacc(v11, aO1);
      hacc(v20, aE0); hacc(v21, aE1);
      hacc(v30, aO0); hacc(v31, aO1);
    }
#pragma unroll
    for (int k = 0; k < 4; k++) {
      aE0[k] = __hadd2(aE0[k], aO0[k]);
      aE1[k] = __hadd2(aE1[k], aO1[k]);
    }
    // scale by dinv of own row -> a2 in A-fragment layout
    __half2 dv = __half2half2(__float2half_rn(dvown));
#pragma unroll
    for (int j = 0; j < 4; j++) {
      aE0[j] = __hmul2(aE0[j], dv);
      aE1[j] = __hmul2(aE1[j], dv);
    }
    half8 a0 = *reinterpret_cast<half8*>(aE0);
    half8 a1 = *reinterpret_cast<half8*>(aE1);

    int g_r[4], t_r[4];
#pragma unroll
    for (int r = 0; r < 4; r++) {
      int nd = __shfl(node, quad * 4 + r);  // original id of C-fragment row
      g_r[r] = nd / 14;
      t_r[r] = nd - g_r[r] * 14;
    }
    float pr[4] = {0.f, 0.f, 0.f, 0.f};
#pragma unroll
    for (int jb = 0; jb < 4; jb++) {
      float4v acc = {0.f, 0.f, 0.f, 0.f};
      acc = __builtin_amdgcn_mfma_f32_16x16x32_f16(a0, bf[jb][0], acc, 0, 0, 0);
      acc = __builtin_amdgcn_mfma_f32_16x16x32_f16(a1, bf[jb][1], acc, 0, 0, 0);
      int j = jb * 16 + n16;
#pragma unroll
      for (int r = 0; r < 4; r++) {
        float h = acc[r] + b2j[jb];
        h = h > 0.f ? h : 0.f;
        pr[r] += h * Wfc[t_r[r] * 64 + j];
      }
    }
#pragma unroll
    for (int r = 0; r < 4; r++) {
#pragma unroll
      for (int off = 1; off < 16; off <<= 1) pr[r] += __shfl_xor(pr[r], off);
    }
    if (n16 == 0) {
#pragma unroll
      for (int r = 0; r < 4; r++) atomicAdd(&out[g_r[r]], pr[r]);
    }
  }
}

extern "C" void kernel_launch(void* const* d_in, const int* in_sizes, int n_in,
                              void* d_out, int out_size, void* d_ws, size_t ws_size,
                              hipStream_t stream)
{
  const float* x = (const float*)d_in[0];
  const int* edges = (const int*)d_in[1];
  const float* W1 = (const float*)d_in[2];
  const float* b1 = (const float*)d_in[3];
  const float* W2 = (const float*)d_in[4];
  const float* b2 = (const float*)d_in[5];
  const float* Wfc = (const float*)d_in[6];
  const float* bfc = (const float*)d_in[7];
  float* out = (float*)d_out;
  (void)n_in;

  const int N = in_sizes[0] / 32;   // 700000
  const int E = in_sizes[1] / 2;    // 4000000
  const int B = out_size;           // 50000
  const int NBK = (N + BNODES - 1) >> BSH;  // 342 buckets (dst>>11)
  const int NCH = (E + CHUNK - 1) / CHUNK;  // 489 chunks
  const int NBLK = (N + 255) / 256;

  char* ws = (char*)d_ws;
  size_t off = 0;
  auto alloc = [&](size_t bytes) -> void* {
    void* p = ws + off;
    off += (bytes + 255) & ~(size_t)255;
    return p;
  };
  int* flag = (int*)alloc(256);
  int* cnt = (int*)alloc((size_t)NCH * NBK * 4);
  int* totals = (int*)alloc((size_t)NBK * 4);
  int* bstart = (int*)alloc(((size_t)NBK + 1) * 4);
  int* col = (int*)alloc(((size_t)E + N + 256) * 4);  // self entries + overread slack
  int* rowptr = (int*)alloc(((size_t)N + 1) * 4);
  float* dinv = (float*)alloc((size_t)N * 4);
  int* dhist = (int*)alloc(DBINS * 4);
  int* dcur = (int*)alloc(DBINS * 4);
  int* perm = (int*)alloc((size_t)N * 4);
  int* iperm = (int*)alloc((size_t)N * 4);
  int2* rowinfo = (int2*)alloc((size_t)N * 8);
  float* dinv_p = (float*)alloc((size_t)N * 4);
  __half* P = (__half*)alloc(((size_t)N + 16) * 32 * 2);   // perm'd dinv*x; head aliased as pairbuf
  __half* F2 = (__half*)alloc(((size_t)N + 16) * 64 * 2);  // perm'd u1
  int* pair = (int*)P;  // pairbuf (E*4 = 16MB) dead before scale_x writes P (44.8MB)

  if (off > ws_size) {
    float v = -(float)(double)(ws_size >> 20);
    fallback_kernel<<<(B + 255) / 256, 256, 0, stream>>>(out, B, v);
    return;
  }

  probe_kernel<<<1, 64, 0, stream>>>(edges, flag);
  zero_dummy_kernel<<<1, 64, 0, stream>>>(P, F2, dhist, N);
  hist2_kernel<<<NCH, 256, 0, stream>>>(edges, E, N, flag, cnt, NBK);
  colscan_kernel<<<NBK, 64, 0, stream>>>(cnt, NCH, NBK, totals);
  scan_totals_kernel<<<1, 512, 0, stream>>>(totals, NBK, bstart, rowptr, N);
  pass3_kernel<<<NCH, 256, 0, stream>>>(edges, E, N, flag, cnt, bstart, pair, NBK);
  build_kernel<<<NBK, 256, 0, stream>>>(pair, bstart, rowptr, dinv, col, N);

  // position-space degree sort: perm/iperm/rowinfo/dinv_p, then remap col values
  deg_hist_kernel<<<NBLK, 256, 0, stream>>>(rowptr, dhist, N);
  deg_scan_kernel<<<1, 64, 0, stream>>>(dhist, dcur);
  deg_place_kernel<<<NBLK, 256, 0, stream>>>(rowptr, dinv, dcur, perm, iperm, rowinfo, dinv_p, N);
  remap_col_kernel<<<4096, 256, 0, stream>>>(col, iperm, rowptr, N);

  int ntiles = (N + 15) / 16;  // 43750 (N divisible by 16)
  scale_x_perm_kernel<<<2048, 256, 0, stream>>>(x, perm, dinv_p, P, N);
  agg1_pos_kernel<<<4096, 256, 0, stream>>>(P, rowinfo, col, dinv_p, W1, b1, F2, ntiles, N);
  out_init_kernel<<<(B + 255) / 256, 256, 0, stream>>>(out, bfc, B);
  mfma_final_fused_kernel<<<4096, 256, 0, stream>>>(F2, rowinfo, col, dinv_p, perm, W2, b2, Wfc,
                                                    out, ntiles, N);
}

// Round 6
// 561.331 us; speedup vs baseline: 1.0716x; 1.0716x over previous
//
#include <hip/hip_runtime.h>
#include <hip/hip_fp16.h>

// GCN: h1 = relu(gcn(x,W1,b1)); h2 = relu(gcn(h1,W2,b2)); out = h2.reshape(B,896)@Wfc + bfc
// Factored BOTH layers past the aggregation (agg commutes with @W):
//   P  = dinv*x (fp16, 32 feat = 64B rows)           <- stage-1 gather table
//   u1 = dinv*relu(dinv*(agg(P)@W1)+b1)  (fp16, 64 feat)
//   out= FC(relu((dinv*agg(u1))@W2+b2))
// CSR via counting sort (b=dst>>11), self-loop in-row, dummy zero row at N.
// POSITION-SPACE DEGREE SORT: tables P,U stored in degree-sorted order, col[] values
// remapped to positions -> uniform-degree 16-row MFMA tiles (minimal gather padding),
// coalesced table writes, contiguous self-gathers.
// LAUNCH-COUNT MINIMIZED (9 kernels): probe inlined into hist2/pass3; zero-init into
// hist2 block 0; degree histogram into build; 64-bin scan into deg_place; remap+scaleP+
// out-init fused into prep_kernel. (~10us per launch on this harness.)
// agg/final use 2-tile pairing (tile w + tile ntiles-1-w): degree-sorted order makes
// light+heavy pairs -> near-uniform per-wave work, no grid-stride tail.

typedef _Float16 half8 __attribute__((ext_vector_type(8)));
typedef float float4v __attribute__((ext_vector_type(4)));

#define CHUNK 8192
#define BSH 11
#define BNODES 2048
#define DBINS 64

__global__ __launch_bounds__(256) void fallback_kernel(float* __restrict__ out, int n, float v)
{
  int i = blockIdx.x * 256 + threadIdx.x;
  if (i < n) out[i] = v;
}

__device__ inline int edges_shift(const int* __restrict__ edges)
{
  // int64 values < 2^31 -> every odd int32 word is 0 (wave-uniform loads, L1 broadcast)
  int orv = edges[1] | edges[3] | edges[5] | edges[7] | edges[9] | edges[11] | edges[13] | edges[15];
  return (orv == 0) ? 1 : 0;
}

// (1) per-chunk bucket histogram -> cnt[chunk][b]; block 0 also zeroes
// dummy rows of P/F2 and the degree-sort scratch (dhist, dcnt).
__global__ __launch_bounds__(256) void hist2_kernel(
    const int* __restrict__ edges, int E, int N,
    int* __restrict__ cnt, int NBK,
    __half* __restrict__ P, __half* __restrict__ F2,
    int* __restrict__ dhist, int* __restrict__ dcnt)
{
  __shared__ int lh[512];
  int t = threadIdx.x;
  int blk = blockIdx.x;
  if (blk == 0) {
    if (t < 8) ((uint2*)(P + (size_t)N * 32))[t] = make_uint2(0, 0);
    else if (t < 24) ((uint2*)(F2 + (size_t)N * 64))[t - 8] = make_uint2(0, 0);
    if (t >= 64 && t < 64 + DBINS) dhist[t - 64] = 0;
    if (t >= 128 && t < 128 + DBINS) dcnt[t - 128] = 0;
  }
  for (int b = t; b < NBK; b += 256) lh[b] = 0;
  __syncthreads();
  int sh = edges_shift(edges);
  int base = blk * CHUNK;
#pragma unroll
  for (int k = 0; k < CHUNK / 256; k++) {
    int e = base + k * 256 + t;
    if (e < E) {
      int d = edges[(E + e) << sh];
      if ((unsigned)d < (unsigned)N) atomicAdd(&lh[d >> BSH], 1);
    }
  }
  __syncthreads();
  for (int b = t; b < NBK; b += 256) cnt[(size_t)blk * NBK + b] = lh[b];
}

// (2) per-bucket exclusive prefix over chunks, in place; totals[b] = column sum
__global__ __launch_bounds__(64) void colscan_kernel(
    int* __restrict__ cnt, int NCH, int NBK, int* __restrict__ totals)
{
  int b = blockIdx.x;
  int lane = threadIdx.x;
  int carry = 0;
  int rounds = (NCH + 63) >> 6;
  for (int r = 0; r < rounds; r++) {
    int blk = r * 64 + lane;
    int v = (blk < NCH) ? cnt[(size_t)blk * NBK + b] : 0;
    int incl = v;
#pragma unroll
    for (int off = 1; off < 64; off <<= 1) {
      int x = __shfl_up(incl, off);
      if (lane >= off) incl += x;
    }
    int excl = incl - v + carry;
    if (blk < NCH) cnt[(size_t)blk * NBK + b] = excl;
    carry += __shfl(incl, 63);
  }
  if (lane == 0) totals[b] = carry;
}

// (3) exclusive scan of bucket totals -> bstart[NBK+1]; rowptr[N] = Ev + N
__global__ __launch_bounds__(512) void scan_totals_kernel(
    const int* __restrict__ totals, int NBK,
    int* __restrict__ bstart, int* __restrict__ rowptr, int N)
{
  __shared__ int sm[512];
  int t = threadIdx.x;
  int v = (t < NBK) ? totals[t] : 0;
  sm[t] = v;
  __syncthreads();
  for (int off = 1; off < 512; off <<= 1) {
    int x = 0;
    if (t >= off) x = sm[t - off];
    __syncthreads();
    if (t >= off) sm[t] += x;
    __syncthreads();
  }
  if (t < NBK) bstart[t] = sm[t] - v;
  if (t == 0) { bstart[NBK] = sm[511]; rowptr[N] = sm[511] + N; }
}

// (4) placement: contiguous runs per (chunk,bucket); packed = src | (dst&2047)<<20
__global__ __launch_bounds__(256) void pass3_kernel(
    const int* __restrict__ edges, int E, int N,
    const int* __restrict__ cnt, const int* __restrict__ bstart,
    int* __restrict__ pair, int NBK)
{
  __shared__ int lcur[512];
  int t = threadIdx.x;
  int blk = blockIdx.x;
  for (int b = t; b < NBK; b += 256)
    lcur[b] = bstart[b] + cnt[(size_t)blk * NBK + b];
  __syncthreads();
  int sh = edges_shift(edges);
  int base = blk * CHUNK;
#pragma unroll
  for (int k = 0; k < CHUNK / 256; k++) {
    int e = base + k * 256 + t;
    if (e < E) {
      int s = edges[e << sh];
      int d = edges[(E + e) << sh];
      if ((unsigned)s < (unsigned)N && (unsigned)d < (unsigned)N) {
        int pos = atomicAdd(&lcur[d >> BSH], 1);
        pair[pos] = s | ((d & (BNODES - 1)) << 20);
      }
    }
  }
}

// (5) per-bucket CSR build with self entry first in each row; also accumulates the
// global degree-bin histogram (bin = min(deg+1, 63)) for the position-space sort.
__global__ __launch_bounds__(256) void build_kernel(
    const int* __restrict__ pair, const int* __restrict__ bstart,
    int* __restrict__ rowptr, float* __restrict__ dinv, int* __restrict__ col,
    int* __restrict__ dhist, int N)
{
  __shared__ int hist[BNODES];
  __shared__ int cur[BNODES];
  __shared__ int sc[256];
  __shared__ int lh2[DBINS];
  int b = blockIdx.x;
  int t = threadIdx.x;
  int pbeg = bstart[b], pend = bstart[b + 1];
  int colbase = pbeg + (b << BSH);
  if (t < DBINS) lh2[t] = 0;
#pragma unroll
  for (int i = 0; i < BNODES / 256; i++) {
    int idx = i * 256 + t;
    int row = (b << BSH) + idx;
    hist[idx] = (row < N) ? 1 : 0;  // self entry
  }
  __syncthreads();
  for (int p = pbeg + t; p < pend; p += 256)
    atomicAdd(&hist[(pair[p] >> 20) & (BNODES - 1)], 1);
  __syncthreads();
  int hv[8];
  int tsum = 0;
#pragma unroll
  for (int i = 0; i < 8; i++) { hv[i] = hist[t * 8 + i]; tsum += hv[i]; }
  sc[t] = tsum;
  __syncthreads();
  for (int off = 1; off < 256; off <<= 1) {
    int x = 0;
    if (t >= off) x = sc[t - off];
    __syncthreads();
    if (t >= off) sc[t] += x;
    __syncthreads();
  }
  int run = sc[t] - tsum;
#pragma unroll
  for (int i = 0; i < 8; i++) {
    int idx = t * 8 + i;
    int rp = colbase + run;
    int row = (b << BSH) + idx;
    if (row < N) {
      rowptr[row] = rp;
      dinv[row] = rsqrtf((float)hv[i]);  // hv = deg + 1 (self included)
      col[rp] = row;                      // self entry at slot 0
      cur[idx] = rp + 1;
      int bin = hv[i] < DBINS ? hv[i] : DBINS - 1;
      atomicAdd(&lh2[bin], 1);
    } else {
      cur[idx] = rp;
    }
    run += hv[i];
  }
  __syncthreads();
  if (t < DBINS && lh2[t]) atomicAdd(&dhist[t], lh2[t]);
  for (int p = pbeg + t; p < pend; p += 256) {
    int v = pair[p];
    int pos = atomicAdd(&cur[(v >> 20) & (BNODES - 1)], 1);
    col[pos] = v & 0xFFFFF;
  }
}

// (6) place nodes into position space grouped by degree bin. Bin bases come from an
// in-block wave scan of dhist; intra-bin cursors from global dcnt atomics.
// Emits perm, iperm, pre-permuted rowinfo {rbeg,rlen} and dinv_p.
__global__ __launch_bounds__(256) void deg_place_kernel(
    const int* __restrict__ rowptr, const float* __restrict__ dinv,
    const int* __restrict__ dhist, int* __restrict__ dcnt,
    int* __restrict__ perm, int* __restrict__ iperm,
    int2* __restrict__ rowinfo, float* __restrict__ dinv_p, int N)
{
  __shared__ int bb[DBINS];
  __shared__ int lh[DBINS];
  __shared__ int lbase[DBINS];
  int t = threadIdx.x;
  if (t < DBINS) {  // wave 0: exclusive scan of dhist -> bin bases
    lh[t] = 0;
    int v = dhist[t];
    int incl = v;
#pragma unroll
    for (int off = 1; off < DBINS; off <<= 1) {
      int x = __shfl_up(incl, off);
      if (t >= off) incl += x;
    }
    bb[t] = incl - v;
  }
  __syncthreads();
  int n = blockIdx.x * 256 + t;
  int b = -1, rbeg = 0, rlen = 0;
  if (n < N) {
    rbeg = rowptr[n];
    rlen = rowptr[n + 1] - rbeg;
    b = rlen < DBINS ? rlen : DBINS - 1;
    atomicAdd(&lh[b], 1);
  }
  __syncthreads();
  if (t < DBINS) lbase[t] = lh[t] ? (bb[t] + atomicAdd(&dcnt[t], lh[t])) : 0;
  __syncthreads();
  if (t < DBINS) lh[t] = lbase[t];  // reuse lh as intra-block cursor
  __syncthreads();
  if (n < N) {
    int pos = atomicAdd(&lh[b], 1);
    perm[pos] = n;
    iperm[n] = pos;
    rowinfo[pos] = make_int2(rbeg, rlen);
    dinv_p[pos] = dinv[n];
  }
}

// (7) FUSED prep: remap col values id->position; P[pos] = dinv_p[pos]*x[perm[pos]] fp16;
// out[g] = bfc. Three independent grid-stride phases.
__global__ __launch_bounds__(256) void prep_kernel(
    int* __restrict__ col, const int* __restrict__ iperm, const int* __restrict__ rowptr,
    const float* __restrict__ X, const int* __restrict__ perm,
    const float* __restrict__ dinv_p, __half* __restrict__ P,
    float* __restrict__ out, const float* __restrict__ bfc, int N, int B)
{
  int idx = blockIdx.x * 256 + threadIdx.x;
  int stride = gridDim.x * 256;
  int total = rowptr[N];  // Ev + N
  for (int k = idx; k < total; k += stride) col[k] = iperm[col[k]];
  int totp = N * 4;
  for (int i = idx; i < totp; i += stride) {
    int pos = i >> 2, part = i & 3;
    int node = perm[pos];
    const float4* xp = (const float4*)(X + (size_t)node * 32 + part * 8);
    float dv = dinv_p[pos];
    float4 v0 = xp[0], v1 = xp[1];
    half8 h;
    h[0] = (_Float16)(dv * v0.x); h[1] = (_Float16)(dv * v0.y);
    h[2] = (_Float16)(dv * v0.z); h[3] = (_Float16)(dv * v0.w);
    h[4] = (_Float16)(dv * v1.x); h[5] = (_Float16)(dv * v1.y);
    h[6] = (_Float16)(dv * v1.z); h[7] = (_Float16)(dv * v1.w);
    *(half8*)(P + (size_t)pos * 32 + part * 8) = h;
  }
  for (int i = idx; i < B; i += stride) out[i] = bfc[0];
}

__device__ inline void hacc(uint4 v, __half2* a)
{
  a[0] = __hadd2(a[0], *reinterpret_cast<__half2*>(&v.x));
  a[1] = __hadd2(a[1], *reinterpret_cast<__half2*>(&v.y));
  a[2] = __hadd2(a[2], *reinterpret_cast<__half2*>(&v.z));
  a[3] = __hadd2(a[3], *reinterpret_cast<__half2*>(&v.w));
}

// (8) FUSED agg1 + W1 matmul + bias + relu + dinv scale, position space.
// 2-tile pairing: wave w does tiles w and ntiles-1-w (light+heavy -> uniform work).
__global__ __launch_bounds__(256) void agg1_pos_kernel(
    const __half* __restrict__ P, const int2* __restrict__ rowinfo,
    const int* __restrict__ col, const float* __restrict__ dinv_p,
    const float* __restrict__ W1, const float* __restrict__ b1,
    __half* __restrict__ U, int ntiles, int ndummy)
{
  int lane = threadIdx.x & 63;
  int n16 = lane & 15;
  int quad = lane >> 4;

  int wid = (blockIdx.x * 256 + threadIdx.x) >> 6;
  int nt2 = (ntiles + 1) >> 1;
  if (wid >= nt2) return;

  half8 bf[4];
#pragma unroll
  for (int jb = 0; jb < 4; jb++)
#pragma unroll
    for (int i = 0; i < 8; i++)
      bf[jb][i] = (_Float16)W1[(quad * 8 + i) * 64 + jb * 16 + n16];
  float b1j[4];
#pragma unroll
  for (int jb = 0; jb < 4; jb++) b1j[jb] = b1[jb * 16 + n16];

  const uint4* P4 = (const uint4*)P;
  _Float16* Uh = (_Float16*)U;
#pragma unroll 1
  for (int it = 0; it < 2; it++) {
    int tile = (it == 0) ? wid : (ntiles - 1 - wid);
    if (it == 1 && tile <= wid) break;
    int ut = __builtin_amdgcn_readfirstlane(tile);
    int base = ut * 16;
    int2 ri = rowinfo[base + n16];
    int rbeg = ri.x, rlen = ri.y;
    float dvown = dinv_p[base + n16];

    __half2 z2 = __float2half2_rn(0.f);
    __half2 aA[4] = {z2, z2, z2, z2};
    __half2 aB[4] = {z2, z2, z2, z2};

    for (int j = 0; __any(j < rlen); j += 8) {
      int c[8];
#pragma unroll
      for (int q = 0; q < 8; q++) {
        int cc = col[rbeg + j + q];  // slack-padded overread ok
        c[q] = (j + q < rlen) ? cc : ndummy;
      }
      uint4 v[8];
#pragma unroll
      for (int q = 0; q < 8; q++) v[q] = P4[((size_t)c[q] << 2) + quad];
#pragma unroll
      for (int q = 0; q < 8; q += 2) { hacc(v[q], aA); hacc(v[q + 1], aB); }
    }
#pragma unroll
    for (int k = 0; k < 4; k++) aA[k] = __hadd2(aA[k], aB[k]);

    half8 a = *reinterpret_cast<half8*>(aA);
    float4v co[4];
#pragma unroll
    for (int jb = 0; jb < 4; jb++) {
      float4v z = {0.f, 0.f, 0.f, 0.f};
      co[jb] = __builtin_amdgcn_mfma_f32_16x16x32_f16(a, bf[jb], z, 0, 0, 0);
    }
#pragma unroll
    for (int r = 0; r < 4; r++) {
      int pos2 = base + quad * 4 + r;            // contiguous -> coalesced store
      float dv = __shfl(dvown, quad * 4 + r);    // dinv_p[pos2]
#pragma unroll
      for (int jb = 0; jb < 4; jb++) {
        float h = dv * co[jb][r] + b1j[jb];
        h = h > 0.f ? h : 0.f;
        Uh[(size_t)pos2 * 64 + jb * 16 + n16] = (_Float16)(dv * h);
      }
    }
  }
}

// (9) FUSED agg2 + layer2-matmul + relu + FC, position space, 2-tile pairing.
__global__ __launch_bounds__(256) void mfma_final_fused_kernel(
    const __half* __restrict__ U, const int2* __restrict__ rowinfo,
    const int* __restrict__ col, const float* __restrict__ dinv_p,
    const int* __restrict__ perm,
    const float* __restrict__ W2, const float* __restrict__ b2,
    const float* __restrict__ Wfc, float* __restrict__ out,
    int ntiles, int ndummy)
{
  int lane = threadIdx.x & 63;
  int n16 = lane & 15;
  int quad = lane >> 4;

  int wid = (blockIdx.x * 256 + threadIdx.x) >> 6;
  int nt2 = (ntiles + 1) >> 1;
  if (wid >= nt2) return;

  half8 bf[4][2];
#pragma unroll
  for (int jb = 0; jb < 4; jb++)
#pragma unroll
    for (int kf = 0; kf < 2; kf++)
#pragma unroll
      for (int i = 0; i < 8; i++)
        bf[jb][kf][i] = (_Float16)W2[(kf * 32 + quad * 8 + i) * 64 + jb * 16 + n16];
  float b2j[4];
#pragma unroll
  for (int jb = 0; jb < 4; jb++) b2j[jb] = b2[jb * 16 + n16];

  const uint4* U4 = (const uint4*)U;
#pragma unroll 1
  for (int it = 0; it < 2; it++) {
    int tile = (it == 0) ? wid : (ntiles - 1 - wid);
    if (it == 1 && tile <= wid) break;
    int ut = __builtin_amdgcn_readfirstlane(tile);
    int base = ut * 16;
    int2 ri = rowinfo[base + n16];
    int rbeg = ri.x, rlen = ri.y;
    int node = perm[base + n16];  // original id (graph/slot decode only)
    float dvown = dinv_p[base + n16];

    __half2 z2 = __float2half2_rn(0.f);
    __half2 aE0[4] = {z2, z2, z2, z2};
    __half2 aE1[4] = {z2, z2, z2, z2};
    __half2 aO0[4] = {z2, z2, z2, z2};
    __half2 aO1[4] = {z2, z2, z2, z2};

    for (int j = 0; __any(j < rlen); j += 4) {
      int c0 = col[rbeg + j];
      int c1 = col[rbeg + j + 1];  // slack-padded overread ok
      int c2 = col[rbeg + j + 2];
      int c3 = col[rbeg + j + 3];
      c0 = (j < rlen) ? c0 : ndummy;
      c1 = (j + 1 < rlen) ? c1 : ndummy;
      c2 = (j + 2 < rlen) ? c2 : ndummy;
      c3 = (j + 3 < rlen) ? c3 : ndummy;
      uint4 v00 = U4[((size_t)c0 << 3) + quad];
      uint4 v01 = U4[((size_t)c0 << 3) + 4 + quad];
      uint4 v10 = U4[((size_t)c1 << 3) + quad];
      uint4 v11 = U4[((size_t)c1 << 3) + 4 + quad];
      uint4 v20 = U4[((size_t)c2 << 3) + quad];
      uint4 v21 = U4[((size_t)c2 << 3) + 4 + quad];
      uint4 v30 = U4[((size_t)c3 << 3) + quad];
      uint4 v31 = U4[((size_t)c3 << 3) + 4 + quad];
      hacc(v00, aE0); hacc(v01, aE1);
      hacc(v10, aO0); hacc(v11, aO1);
      hacc(v20, aE0); hacc(v21, aE1);
      hacc(v30, aO0); hacc(v31, aO1);
    }
#pragma unroll
    for (int k = 0; k < 4; k++) {
      aE0[k] = __hadd2(aE0[k], aO0[k]);
      aE1[k] = __hadd2(aE1[k], aO1[k]);
    }
    __half2 dv = __half2half2(__float2half_rn(dvown));
#pragma unroll
    for (int j = 0; j < 4; j++) {
      aE0[j] = __hmul2(aE0[j], dv);
      aE1[j] = __hmul2(aE1[j], dv);
    }
    half8 a0 = *reinterpret_cast<half8*>(aE0);
    half8 a1 = *reinterpret_cast<half8*>(aE1);

    int g_r[4], t_r[4];
#pragma unroll
    for (int r = 0; r < 4; r++) {
      int nd = __shfl(node, quad * 4 + r);  // original id of C-fragment row
      g_r[r] = nd / 14;
      t_r[r] = nd - g_r[r] * 14;
    }
    float pr[4] = {0.f, 0.f, 0.f, 0.f};
#pragma unroll
    for (int jb = 0; jb < 4; jb++) {
      float4v acc = {0.f, 0.f, 0.f, 0.f};
      acc = __builtin_amdgcn_mfma_f32_16x16x32_f16(a0, bf[jb][0], acc, 0, 0, 0);
      acc = __builtin_amdgcn_mfma_f32_16x16x32_f16(a1, bf[jb][1], acc, 0, 0, 0);
      int j = jb * 16 + n16;
#pragma unroll
      for (int r = 0; r < 4; r++) {
        float h = acc[r] + b2j[jb];
        h = h > 0.f ? h : 0.f;
        pr[r] += h * Wfc[t_r[r] * 64 + j];
      }
    }
#pragma unroll
    for (int r = 0; r < 4; r++) {
#pragma unroll
      for (int off = 1; off < 16; off <<= 1) pr[r] += __shfl_xor(pr[r], off);
    }
    if (n16 == 0) {
#pragma unroll
      for (int r = 0; r < 4; r++) atomicAdd(&out[g_r[r]], pr[r]);
    }
  }
}

extern "C" void kernel_launch(void* const* d_in, const int* in_sizes, int n_in,
                              void* d_out, int out_size, void* d_ws, size_t ws_size,
                              hipStream_t stream)
{
  const float* x = (const float*)d_in[0];
  const int* edges = (const int*)d_in[1];
  const float* W1 = (const float*)d_in[2];
  const float* b1 = (const float*)d_in[3];
  const float* W2 = (const float*)d_in[4];
  const float* b2 = (const float*)d_in[5];
  const float* Wfc = (const float*)d_in[6];
  const float* bfc = (const float*)d_in[7];
  float* out = (float*)d_out;
  (void)n_in;

  const int N = in_sizes[0] / 32;   // 700000
  const int E = in_sizes[1] / 2;    // 4000000
  const int B = out_size;           // 50000
  const int NBK = (N + BNODES - 1) >> BSH;  // 342 buckets (dst>>11)
  const int NCH = (E + CHUNK - 1) / CHUNK;  // 489 chunks
  const int NBLK = (N + 255) / 256;

  char* ws = (char*)d_ws;
  size_t off = 0;
  auto alloc = [&](size_t bytes) -> void* {
    void* p = ws + off;
    off += (bytes + 255) & ~(size_t)255;
    return p;
  };
  int* cnt = (int*)alloc((size_t)NCH * NBK * 4);
  int* totals = (int*)alloc((size_t)NBK * 4);
  int* bstart = (int*)alloc(((size_t)NBK + 1) * 4);
  int* col = (int*)alloc(((size_t)E + N + 256) * 4);  // self entries + overread slack
  int* rowptr = (int*)alloc(((size_t)N + 1) * 4);
  float* dinv = (float*)alloc((size_t)N * 4);
  int* dhist = (int*)alloc(DBINS * 4);
  int* dcnt = (int*)alloc(DBINS * 4);
  int* perm = (int*)alloc((size_t)N * 4);
  int* iperm = (int*)alloc((size_t)N * 4);
  int2* rowinfo = (int2*)alloc((size_t)N * 8);
  float* dinv_p = (float*)alloc((size_t)N * 4);
  __half* P = (__half*)alloc(((size_t)N + 16) * 32 * 2);   // perm'd dinv*x; head aliased as pairbuf
  __half* F2 = (__half*)alloc(((size_t)N + 16) * 64 * 2);  // perm'd u1
  int* pair = (int*)P;  // pairbuf (E*4 = 16MB) dead before prep writes P (44.8MB)

  if (off > ws_size) {
    float v = -(float)(double)(ws_size >> 20);
    fallback_kernel<<<(B + 255) / 256, 256, 0, stream>>>(out, B, v);
    return;
  }

  hist2_kernel<<<NCH, 256, 0, stream>>>(edges, E, N, cnt, NBK, P, F2, dhist, dcnt);
  colscan_kernel<<<NBK, 64, 0, stream>>>(cnt, NCH, NBK, totals);
  scan_totals_kernel<<<1, 512, 0, stream>>>(totals, NBK, bstart, rowptr, N);
  pass3_kernel<<<NCH, 256, 0, stream>>>(edges, E, N, cnt, bstart, pair, NBK);
  build_kernel<<<NBK, 256, 0, stream>>>(pair, bstart, rowptr, dinv, col, dhist, N);
  deg_place_kernel<<<NBLK, 256, 0, stream>>>(rowptr, dinv, dhist, dcnt,
                                             perm, iperm, rowinfo, dinv_p, N);
  prep_kernel<<<4096, 256, 0, stream>>>(col, iperm, rowptr, x, perm, dinv_p, P,
                                        out, bfc, N, B);

  int ntiles = (N + 15) / 16;       // 43750
  int nt2 = (ntiles + 1) >> 1;      // paired waves
  int gblk = (nt2 + 3) / 4;         // 4 waves per block
  agg1_pos_kernel<<<gblk, 256, 0, stream>>>(P, rowinfo, col, dinv_p, W1, b1, F2, ntiles, N);
  mfma_final_fused_kernel<<<gblk, 256, 0, stream>>>(F2, rowinfo, col, dinv_p, perm, W2, b2, Wfc,
                                                    out, ntiles, N);
}